// Round 1
// baseline (52.901 us; speedup 1.0000x reference)
//
#include <hip/hip_runtime.h>

// out[n][f] = class_bias[f][ idx[n][f] ] + global_bias[f]
// N=1048576, F=16, C=1024. Memory-bound: 64 MiB idx read + 64 MiB out write.
// Table (64 KiB) is cache-resident; random gather from it costs latency only,
// hidden by TLP (2048 blocks * 256 thr, grid-stride).

constexpr int kC = 1024;

__global__ __launch_bounds__(256) void onehot_gather_kernel(
    const int4* __restrict__ idx4,
    const float* __restrict__ cb,   // [16][1024]
    const float* __restrict__ gb,   // [16]
    float4* __restrict__ out4,
    int total4)                     // (N*F)/4
{
    const int stride = gridDim.x * blockDim.x;
    for (int t = blockIdx.x * blockDim.x + threadIdx.x; t < total4; t += stride) {
        int4 v = idx4[t];
        // Element base = t*4; feature of element j is (t*4 + j) % 16.
        // 4 | 16, so the 4 features are consecutive: f0 = (t%4)*4.
        const int f0 = (t & 3) << 2;
        float4 o;
        o.x = cb[(f0 + 0) * kC + v.x] + gb[f0 + 0];
        o.y = cb[(f0 + 1) * kC + v.y] + gb[f0 + 1];
        o.z = cb[(f0 + 2) * kC + v.z] + gb[f0 + 2];
        o.w = cb[(f0 + 3) * kC + v.w] + gb[f0 + 3];
        out4[t] = o;
    }
}

extern "C" void kernel_launch(void* const* d_in, const int* in_sizes, int n_in,
                              void* d_out, int out_size, void* d_ws, size_t ws_size,
                              hipStream_t stream) {
    const int4*  idx4 = (const int4*)d_in[0];   // [N,F] int32, viewed as int4
    const float* cb   = (const float*)d_in[1];  // [F,C] f32
    const float* gb   = (const float*)d_in[2];  // [F] f32
    float4* out4 = (float4*)d_out;              // [N,F] f32, viewed as float4

    const int total4 = out_size / 4;            // 4,194,304
    const int block  = 256;
    const int grid   = 2048;                    // grid-stride, ~8 iters/thread
    onehot_gather_kernel<<<grid, block, 0, stream>>>(idx4, cb, gb, out4, total4);
}

// Round 3
// 27.694 us; speedup vs baseline: 1.9102x; 1.9102x over previous
//
#include <hip/hip_runtime.h>

// out[n][f] = class_bias[f][ idx[n][f] ] + global_bias[f]
// N=1048576, F=16, C=1024.
// R1 insight: scattered global gathers from the 64 KiB table thrash L1 and
// amplify ~16x at L2 (dword use per 64B line) -> latency/L2-bound at 53 us.
// Fix: stage (class_bias + global_bias) into 64 KiB LDS per block; gathers go
// to the LDS pipe, vmem pipe does pure coalesced streaming.
// Block = 1024 thr (16 waves), 64 KiB LDS -> 2 blocks/CU = 32 waves/CU (100%).
// R2 fix: nontemporal builtins need true clang vector types, not HIP_vector_type.

constexpr int kC = 1024;
constexpr int kF = 16;
constexpr int kTab = kF * kC;          // 16384 floats = 64 KiB

typedef int   v4i __attribute__((ext_vector_type(4)));
typedef float v4f __attribute__((ext_vector_type(4)));

__global__ __launch_bounds__(1024) void onehot_lds_kernel(
    const v4i* __restrict__ idx4,
    const v4f* __restrict__ cb4,       // [16][1024] f32 viewed as v4f
    const float* __restrict__ gb,      // [16]
    v4f* __restrict__ out4,
    int total4)                        // (N*F)/4
{
    __shared__ float lut[kTab];

    // Stage table with bias fused: 16384 floats / 1024 threads = 4 v4f each.
    {
        v4f* lut4 = (v4f*)lut;
        #pragma unroll
        for (int j = 0; j < 4; ++j) {
            int p = threadIdx.x + j * 1024;      // v4f slot in [0, 4096)
            int f = p >> 8;                      // 256 v4f per feature row
            v4f v = cb4[p];
            float b = gb[f];
            v.x += b; v.y += b; v.z += b; v.w += b;
            lut4[p] = v;
        }
    }
    __syncthreads();

    const int S = gridDim.x * blockDim.x;
    int t = blockIdx.x * blockDim.x + threadIdx.x;

    // 2-way batched grid-stride: two independent idx loads in flight.
    for (; t + S < total4; t += 2 * S) {
        v4i a = __builtin_nontemporal_load(&idx4[t]);
        v4i b = __builtin_nontemporal_load(&idx4[t + S]);
        const int fa = (t & 3) << 2;             // S % 4 == 0 in our launch,
        const int fb = ((t + S) & 3) << 2;       // but compute both anyway
        v4f oa, ob;
        oa.x = lut[(fa + 0) * kC + a.x];
        oa.y = lut[(fa + 1) * kC + a.y];
        oa.z = lut[(fa + 2) * kC + a.z];
        oa.w = lut[(fa + 3) * kC + a.w];
        ob.x = lut[(fb + 0) * kC + b.x];
        ob.y = lut[(fb + 1) * kC + b.y];
        ob.z = lut[(fb + 2) * kC + b.z];
        ob.w = lut[(fb + 3) * kC + b.w];
        __builtin_nontemporal_store(oa, &out4[t]);
        __builtin_nontemporal_store(ob, &out4[t + S]);
    }
    for (; t < total4; t += S) {
        v4i a = __builtin_nontemporal_load(&idx4[t]);
        const int fa = (t & 3) << 2;
        v4f oa;
        oa.x = lut[(fa + 0) * kC + a.x];
        oa.y = lut[(fa + 1) * kC + a.y];
        oa.z = lut[(fa + 2) * kC + a.z];
        oa.w = lut[(fa + 3) * kC + a.w];
        __builtin_nontemporal_store(oa, &out4[t]);
    }
}

extern "C" void kernel_launch(void* const* d_in, const int* in_sizes, int n_in,
                              void* d_out, int out_size, void* d_ws, size_t ws_size,
                              hipStream_t stream) {
    const v4i* idx4 = (const v4i*)d_in[0];      // [N,F] int32 viewed as v4i
    const v4f* cb4  = (const v4f*)d_in[1];      // [F,C] f32
    const float* gb = (const float*)d_in[2];    // [F] f32
    v4f* out4 = (v4f*)d_out;

    const int total4 = out_size / 4;            // 4,194,304
    const int block  = 1024;                    // 16 waves; 64 KiB LDS -> 2 blk/CU
    const int grid   = 512;                     // 2 per CU; 8 iters/thread
    onehot_lds_kernel<<<grid, block, 0, stream>>>(idx4, cb4, gb, out4, total4);
}